// Round 1
// baseline (220.070 us; speedup 1.0000x reference)
//
#include <hip/hip_runtime.h>
#include <hip/hip_bf16.h>
#include <cstdint>
#include <cstddef>

// ---------- types ----------
typedef __bf16 bf16x8 __attribute__((ext_vector_type(8)));
typedef float f32x4 __attribute__((ext_vector_type(4)));

__device__ __forceinline__ void gload_lds16(const void* g, void* l) {
  __builtin_amdgcn_global_load_lds((const __attribute__((address_space(1))) void*)g,
                                   (__attribute__((address_space(3))) void*)l, 16, 0, 0);
}

// ---------- kernel 1: sqrt(Fc) = sqrt(sum_|X| over spatial) ----------
// rows: [t(2)][b(16)][c(512)] = 16384 rows of 1024 floats. 4 rows/block (1 wave each).
__global__ void fc_kernel(const float* __restrict__ TF, const float* __restrict__ SF,
                          float* __restrict__ sqrtFc) {
  int wv = threadIdx.x >> 6, lane = threadIdx.x & 63;
  int row = blockIdx.x * 4 + wv;                 // [0, 16384)
  const float* X = (row < 8192) ? TF : SF;
  const float* p = X + (size_t)(row & 8191) * 1024;
  float s = 0.f;
#pragma unroll
  for (int it = 0; it < 4; ++it) {
    float4 v = *reinterpret_cast<const float4*>(p + (size_t)(it * 64 + lane) * 4);
    s += fabsf(v.x) + fabsf(v.y) + fabsf(v.z) + fabsf(v.w);
  }
#pragma unroll
  for (int m = 32; m; m >>= 1) s += __shfl_xor(s, m);
  if (lane == 0) sqrtFc[row] = sqrtf(s);
}

// ---------- kernel 2: W[b][m][c] = bf16( X[b][c][m] * sqrtFc[b][c] ) (transpose) ----------
__global__ void wprep_kernel(const float* __restrict__ TF, const float* __restrict__ SF,
                             const float* __restrict__ sqrtFc,
                             __hip_bfloat16* __restrict__ Wt, __hip_bfloat16* __restrict__ Ws) {
  __shared__ float lds[32][33];
  int z = blockIdx.z;                // t*16 + b
  int t = z >> 4, b = z & 15;
  int m0 = blockIdx.x * 32, c0 = blockIdx.y * 32;
  const float* X = ((t ? SF : TF) + (size_t)b * 512 * 1024);
  __hip_bfloat16* W = ((t ? Ws : Wt) + (size_t)b * 1024 * 512);
  int tr = threadIdx.x >> 5, tc = threadIdx.x & 31;
#pragma unroll
  for (int i = 0; i < 4; ++i) {
    int r = i * 8 + tr;
    lds[r][tc] = X[(size_t)(c0 + r) * 1024 + m0 + tc];
  }
  __syncthreads();
  float scale = sqrtFc[t * 8192 + b * 512 + c0 + tc];
#pragma unroll
  for (int i = 0; i < 4; ++i) {
    int m = i * 8 + tr;
    W[(size_t)(m0 + m) * 512 + (c0 + tc)] = __float2bfloat16(lds[tc][m] * scale);
  }
}

// ---------- SYRK tile: acc += W[tm-tile] * W[tn-tile]^T, K=512, BK=64, BM=BN=128 ----------
// W layout: [1024][512] bf16 per batch (K contiguous). 256 threads = 4 waves (2x2).
__device__ __forceinline__ void syrk_tile(const __hip_bfloat16* __restrict__ Wb,
                                          __hip_bfloat16* As, __hip_bfloat16* Bs,
                                          int tm, int tn, f32x4 (&acc)[4][4]) {
  const int tid = threadIdx.x;
  const int lane = tid & 63, wv = tid >> 6;
  const int wr = wv >> 1, wc = wv & 1;
  const int g = lane >> 4, c0 = lane & 15;
  for (int kt = 0; kt < 8; ++kt) {
#pragma unroll
    for (int i = 0; i < 4; ++i) {
      int ci = i * 256 + tid;          // chunk id (16B chunks), 1024 per tile
      int row = ci >> 3, ch = ci & 7;
      const __hip_bfloat16* gA = Wb + (size_t)(tm * 128 + row) * 512 + kt * 64 + ch * 8;
      const __hip_bfloat16* gB = Wb + (size_t)(tn * 128 + row) * 512 + kt * 64 + ch * 8;
      int wbase = (i * 256 + wv * 64) * 8;   // wave-uniform LDS element base
      gload_lds16(gA, As + wbase);
      gload_lds16(gB, Bs + wbase);
    }
    __syncthreads();
#pragma unroll
    for (int kk = 0; kk < 2; ++kk) {
      bf16x8 a[4], bb[4];
#pragma unroll
      for (int mi = 0; mi < 4; ++mi)
        a[mi] = *reinterpret_cast<const bf16x8*>(As + (size_t)(wr * 64 + mi * 16 + c0) * 64 + kk * 32 + g * 8);
#pragma unroll
      for (int ni = 0; ni < 4; ++ni)
        bb[ni] = *reinterpret_cast<const bf16x8*>(Bs + (size_t)(wc * 64 + ni * 16 + c0) * 64 + kk * 32 + g * 8);
#pragma unroll
      for (int mi = 0; mi < 4; ++mi)
#pragma unroll
        for (int ni = 0; ni < 4; ++ni)
          acc[mi][ni] = __builtin_amdgcn_mfma_f32_16x16x32_bf16(a[mi], bb[ni], acc[mi][ni], 0, 0, 0);
    }
    __syncthreads();
  }
}

// ---------- kernel 3 (phase 1): row norms norm2[t][b][m] = sum_n A[m,n]^2 ----------
__global__ void __launch_bounds__(256, 2) syrk_norm_kernel(
    const __hip_bfloat16* __restrict__ Wt, const __hip_bfloat16* __restrict__ Ws,
    float* __restrict__ norm2) {
  __shared__ __hip_bfloat16 As[128 * 64], Bs[128 * 64];
  int z = blockIdx.z;                  // t*16 + b
  int t = z >> 4, b = z & 15;
  const __hip_bfloat16* Wb = (t ? Ws : Wt) + (size_t)b * 1024 * 512;
  int tm = blockIdx.x, tn = blockIdx.y;
  f32x4 acc[4][4];
#pragma unroll
  for (int mi = 0; mi < 4; ++mi)
#pragma unroll
    for (int ni = 0; ni < 4; ++ni) acc[mi][ni] = (f32x4){0.f, 0.f, 0.f, 0.f};
  syrk_tile(Wb, As, Bs, tm, tn, acc);

  int lane = threadIdx.x & 63, wv = threadIdx.x >> 6;
  int wr = wv >> 1, g = lane >> 4, c0 = lane & 15;
  float* nb = norm2 + (size_t)z * 1024;
#pragma unroll
  for (int mi = 0; mi < 4; ++mi)
#pragma unroll
    for (int r = 0; r < 4; ++r) {
      float s = 0.f;
#pragma unroll
      for (int ni = 0; ni < 4; ++ni) { float v = acc[mi][ni][r]; s += v * v; }
      s += __shfl_xor(s, 1); s += __shfl_xor(s, 2);
      s += __shfl_xor(s, 4); s += __shfl_xor(s, 8);
      if (c0 == 0) atomicAdd(nb + tm * 128 + wr * 64 + mi * 16 + g * 4 + r, s);
    }
}

// ---------- kernel 4 (phase 2): recompute A_T, A_S tiles; sum (A_S/nS - A_T/nT)^2 ----------
__global__ void __launch_bounds__(256, 2) syrk_diff_kernel(
    const __hip_bfloat16* __restrict__ Wt, const __hip_bfloat16* __restrict__ Ws,
    const float* __restrict__ norm2, float* __restrict__ sa_sum) {
  __shared__ __hip_bfloat16 As[128 * 64], Bs[128 * 64];
  __shared__ float red[4];
  int b = blockIdx.z;
  int tm = blockIdx.x, tn = blockIdx.y;
  f32x4 accT[4][4], accS[4][4];
#pragma unroll
  for (int mi = 0; mi < 4; ++mi)
#pragma unroll
    for (int ni = 0; ni < 4; ++ni) {
      accT[mi][ni] = (f32x4){0.f, 0.f, 0.f, 0.f};
      accS[mi][ni] = (f32x4){0.f, 0.f, 0.f, 0.f};
    }
  syrk_tile(Wt + (size_t)b * 1024 * 512, As, Bs, tm, tn, accT);
  syrk_tile(Ws + (size_t)b * 1024 * 512, As, Bs, tm, tn, accS);

  int lane = threadIdx.x & 63, wv = threadIdx.x >> 6;
  int wr = wv >> 1, g = lane >> 4;
  const float* n2T = norm2 + (size_t)b * 1024;
  const float* n2S = norm2 + 16384 + (size_t)b * 1024;
  float local = 0.f;
#pragma unroll
  for (int mi = 0; mi < 4; ++mi)
#pragma unroll
    for (int r = 0; r < 4; ++r) {
      int m = tm * 128 + wr * 64 + mi * 16 + g * 4 + r;
      float rT = 1.f / fmaxf(sqrtf(n2T[m]), 1e-12f);
      float rS = 1.f / fmaxf(sqrtf(n2S[m]), 1e-12f);
#pragma unroll
      for (int ni = 0; ni < 4; ++ni) {
        float d = accS[mi][ni][r] * rS - accT[mi][ni][r] * rT;
        local += d * d;
      }
    }
#pragma unroll
  for (int m = 32; m; m >>= 1) local += __shfl_xor(local, m);
  if (lane == 0) red[wv] = local;
  __syncthreads();
  if (threadIdx.x == 0) atomicAdd(sa_sum, red[0] + red[1] + red[2] + red[3]);
}

// ---------- kernel 5: channel grams G[t][b][i][j] = <L_i, L_j> (len 16384) ----------
__global__ void icgram_kernel(const float* __restrict__ t_out, const float* __restrict__ s_out,
                              float* __restrict__ G) {
  __shared__ float Li[16384];
  __shared__ float red[4];
  int i = blockIdx.x, b = blockIdx.y, t = blockIdx.z;
  const float* L = (t ? s_out : t_out) + (size_t)b * 21 * 16384;
  int tid = threadIdx.x, lane = tid & 63, wv = tid >> 6;
#pragma unroll
  for (int it = 0; it < 16; ++it) {
    int idx = (it * 256 + tid) * 4;
    *reinterpret_cast<float4*>(Li + idx) = *reinterpret_cast<const float4*>(L + (size_t)i * 16384 + idx);
  }
  __syncthreads();
  float* Gout = G + ((size_t)(t * 16 + b) * 21 + i) * 21;
  for (int j = 0; j < 21; ++j) {
    const float* Lj = L + (size_t)j * 16384;
    float s = 0.f;
#pragma unroll
    for (int it = 0; it < 16; ++it) {
      int idx = (it * 256 + tid) * 4;
      float4 v = *reinterpret_cast<const float4*>(Lj + idx);
      s += v.x * Li[idx] + v.y * Li[idx + 1] + v.z * Li[idx + 2] + v.w * Li[idx + 3];
    }
#pragma unroll
    for (int m = 32; m; m >>= 1) s += __shfl_xor(s, m);
    if (lane == 0) red[wv] = s;
    __syncthreads();
    if (tid == 0) Gout[j] = red[0] + red[1] + red[2] + red[3];
    __syncthreads();
  }
}

// ---------- kernel 6: finalize both losses ----------
__global__ void finalize_kernel(const float* __restrict__ G, const float* __restrict__ sa_sum,
                                float* __restrict__ out2) {
  __shared__ float red[8];
  int tid = threadIdx.x;   // 512 threads
  float local = 0.f;
  if (tid < 336) {
    int b = tid / 21, i = tid % 21;
    const float* gt = G + ((size_t)b * 21 + i) * 21;
    const float* gs = G + ((size_t)(16 + b) * 21 + i) * 21;
    float nt = 0.f, ns = 0.f;
    for (int j = 0; j < 21; ++j) { nt += gt[j] * gt[j]; ns += gs[j] * gs[j]; }
    float rt = 1.f / fmaxf(sqrtf(nt), 1e-12f);
    float rs = 1.f / fmaxf(sqrtf(ns), 1e-12f);
    for (int j = 0; j < 21; ++j) { float d = gs[j] * rs - gt[j] * rt; local += d * d; }
  }
  int lane = tid & 63, wv = tid >> 6;
#pragma unroll
  for (int m = 32; m; m >>= 1) local += __shfl_xor(local, m);
  if (lane == 0) red[wv] = local;
  __syncthreads();
  if (tid == 0) {
    float ic = 0.f;
    for (int w = 0; w < 8; ++w) ic += red[w];
    out2[0] = ic * (1.0f / 336.0f);                // ic_loss / (21*16)
    out2[1] = sa_sum[0] * (1.0f / 16777216.0f);    // SA_loss / (16*1024^2)
  }
}

// ---------- launch ----------
extern "C" void kernel_launch(void* const* d_in, const int* in_sizes, int n_in,
                              void* d_out, int out_size, void* d_ws, size_t ws_size,
                              hipStream_t stream) {
  const float* TF = (const float*)d_in[0];
  const float* SF = (const float*)d_in[1];
  const float* t_out = (const float*)d_in[2];
  const float* s_out = (const float*)d_in[3];
  float* out = (float*)d_out;
  char* ws = (char*)d_ws;

  // ws layout (bytes):
  //   0       : norm2 [2][16][1024] f32   (131072)
  //   131072  : sa_sum f32                (pad to 256)
  //   131328  : sqrtFc [2][16][512] f32   (65536)
  //   196864  : G [2][16][21][21] f32     (56448)
  //   262144  : Wt bf16 [16][1024][512]   (16777216)
  //   17039360: Ws bf16 [16][1024][512]   (16777216)  -> total 33,816,576 B
  float* norm2 = (float*)(ws + 0);
  float* sa_sum = (float*)(ws + 131072);
  float* sqrtFc = (float*)(ws + 131328);
  float* G = (float*)(ws + 196864);
  __hip_bfloat16* Wt = (__hip_bfloat16*)(ws + 262144);
  __hip_bfloat16* Ws = (__hip_bfloat16*)(ws + 262144 + 16777216);

  // s_out passthrough
  hipMemcpyAsync(d_out, (const void*)s_out, (size_t)5505024 * 4, hipMemcpyDeviceToDevice, stream);
  // zero accumulators (norm2 + sa_sum)
  hipMemsetAsync(norm2, 0, 131072 + 256, stream);

  fc_kernel<<<4096, 256, 0, stream>>>(TF, SF, sqrtFc);
  wprep_kernel<<<dim3(32, 16, 32), 256, 0, stream>>>(TF, SF, sqrtFc, Wt, Ws);
  syrk_norm_kernel<<<dim3(8, 8, 32), 256, 0, stream>>>(Wt, Ws, norm2);
  syrk_diff_kernel<<<dim3(8, 8, 16), 256, 0, stream>>>(Wt, Ws, norm2, sa_sum);
  icgram_kernel<<<dim3(21, 16, 2), 256, 0, stream>>>(t_out, s_out, G);
  finalize_kernel<<<1, 512, 0, stream>>>(G, sa_sum, out + 5505024);
}

// Round 2
// 152.682 us; speedup vs baseline: 1.4414x; 1.4414x over previous
//
#include <hip/hip_runtime.h>
#include <hip/hip_bf16.h>
#include <cstdint>
#include <cstddef>

// ---------- types ----------
typedef __bf16 bf16x8 __attribute__((ext_vector_type(8)));
typedef float f32x4 __attribute__((ext_vector_type(4)));

__device__ __forceinline__ void gload_lds16(const void* g, void* l) {
  __builtin_amdgcn_global_load_lds((const __attribute__((address_space(1))) void*)g,
                                   (__attribute__((address_space(3))) void*)l, 16, 0, 0);
}

// ---------- kernel 1: sqrt(Fc) = sqrt(sum_|X| over spatial) ----------
__global__ void fc_kernel(const float* __restrict__ TF, const float* __restrict__ SF,
                          float* __restrict__ sqrtFc) {
  int wv = threadIdx.x >> 6, lane = threadIdx.x & 63;
  int row = blockIdx.x * 4 + wv;                 // [0, 16384)
  const float* X = (row < 8192) ? TF : SF;
  const float* p = X + (size_t)(row & 8191) * 1024;
  float s = 0.f;
#pragma unroll
  for (int it = 0; it < 4; ++it) {
    float4 v = *reinterpret_cast<const float4*>(p + (size_t)(it * 64 + lane) * 4);
    s += fabsf(v.x) + fabsf(v.y) + fabsf(v.z) + fabsf(v.w);
  }
#pragma unroll
  for (int m = 32; m; m >>= 1) s += __shfl_xor(s, m);
  if (lane == 0) sqrtFc[row] = sqrtf(s);
}

// ---------- kernel 2: W[b][m][c] = bf16( X[b][c][m] * sqrtFc[b][c] ) ----------
__global__ void wprep_kernel(const float* __restrict__ TF, const float* __restrict__ SF,
                             const float* __restrict__ sqrtFc,
                             __hip_bfloat16* __restrict__ Wt, __hip_bfloat16* __restrict__ Ws) {
  __shared__ float lds[32][33];
  int z = blockIdx.z;                // t*16 + b
  int t = z >> 4, b = z & 15;
  int m0 = blockIdx.x * 32, c0 = blockIdx.y * 32;
  const float* X = ((t ? SF : TF) + (size_t)b * 512 * 1024);
  __hip_bfloat16* W = ((t ? Ws : Wt) + (size_t)b * 1024 * 512);
  int tr = threadIdx.x >> 5, tc = threadIdx.x & 31;
#pragma unroll
  for (int i = 0; i < 4; ++i) {
    int r = i * 8 + tr;
    lds[r][tc] = X[(size_t)(c0 + r) * 1024 + m0 + tc];
  }
  __syncthreads();
  float scale = sqrtFc[t * 8192 + b * 512 + c0 + tc];
#pragma unroll
  for (int i = 0; i < 4; ++i) {
    int m = i * 8 + tr;
    W[(size_t)(m0 + m) * 512 + (c0 + tc)] = __float2bfloat16(lds[tc][m] * scale);
  }
}

// ---------- SYRK tile: acc += W[tm-tile] * W[tn-tile]^T, K=512, BK=64, BM=BN=128 ----------
__device__ __forceinline__ void syrk_tile(const __hip_bfloat16* __restrict__ Wb,
                                          __hip_bfloat16* As, __hip_bfloat16* Bs,
                                          int tm, int tn, f32x4 (&acc)[4][4]) {
  const int tid = threadIdx.x;
  const int lane = tid & 63, wv = tid >> 6;
  const int wr = wv >> 1, wc = wv & 1;
  const int g = lane >> 4, c0 = lane & 15;
  const __hip_bfloat16* Bsrc = (tm == tn) ? As : Bs;
  for (int kt = 0; kt < 8; ++kt) {
#pragma unroll
    for (int i = 0; i < 4; ++i) {
      int ci = i * 256 + tid;          // chunk id (16B chunks), 1024 per tile
      int row = ci >> 3, ch = ci & 7;
      int wbase = (i * 256 + wv * 64) * 8;   // wave-uniform LDS element base
      gload_lds16(Wb + (size_t)(tm * 128 + row) * 512 + kt * 64 + ch * 8, As + wbase);
      if (tm != tn)
        gload_lds16(Wb + (size_t)(tn * 128 + row) * 512 + kt * 64 + ch * 8, Bs + wbase);
    }
    __syncthreads();
#pragma unroll
    for (int kk = 0; kk < 2; ++kk) {
      bf16x8 a[4], bb[4];
#pragma unroll
      for (int mi = 0; mi < 4; ++mi)
        a[mi] = *reinterpret_cast<const bf16x8*>(As + (size_t)(wr * 64 + mi * 16 + c0) * 64 + kk * 32 + g * 8);
#pragma unroll
      for (int ni = 0; ni < 4; ++ni)
        bb[ni] = *reinterpret_cast<const bf16x8*>(Bsrc + (size_t)(wc * 64 + ni * 16 + c0) * 64 + kk * 32 + g * 8);
#pragma unroll
      for (int mi = 0; mi < 4; ++mi)
#pragma unroll
        for (int ni = 0; ni < 4; ++ni)
          acc[mi][ni] = __builtin_amdgcn_mfma_f32_16x16x32_bf16(a[mi], bb[ni], acc[mi][ni], 0, 0, 0);
    }
    __syncthreads();
  }
}

// ---------- kernel 3: fused SYRK pass: accumulate ||A_T row||^2, ||A_S row||^2, cross ----------
__global__ void __launch_bounds__(256, 2) syrk_fused_kernel(
    const __hip_bfloat16* __restrict__ Wt, const __hip_bfloat16* __restrict__ Ws,
    float* __restrict__ nT, float* __restrict__ nS, float* __restrict__ cross) {
  __shared__ __hip_bfloat16 As[128 * 64], Bs[128 * 64];
  int b = blockIdx.z;
  // decode upper-triangle tile pair (tm <= tn) from blockIdx.x in [0,36)
  int bx = blockIdx.x, tm = 0;
  while (bx >= 8 - tm) { bx -= 8 - tm; tm++; }
  int tn = tm + bx;
  f32x4 accT[4][4], accS[4][4];
#pragma unroll
  for (int mi = 0; mi < 4; ++mi)
#pragma unroll
    for (int ni = 0; ni < 4; ++ni) {
      accT[mi][ni] = (f32x4){0.f, 0.f, 0.f, 0.f};
      accS[mi][ni] = (f32x4){0.f, 0.f, 0.f, 0.f};
    }
  syrk_tile(Wt + (size_t)b * 524288, As, Bs, tm, tn, accT);
  syrk_tile(Ws + (size_t)b * 524288, As, Bs, tm, tn, accS);

  int lane = threadIdx.x & 63, wv = threadIdx.x >> 6;
  int wr = wv >> 1, wc = wv & 1, g = lane >> 4, c0 = lane & 15;
  float* pT = nT + (size_t)b * 1024;
  float* pS = nS + (size_t)b * 1024;
  float* pC = cross + (size_t)b * 1024;
  // row-direction sums (over columns of this tile)
#pragma unroll
  for (int mi = 0; mi < 4; ++mi)
#pragma unroll
    for (int r = 0; r < 4; ++r) {
      float sT = 0.f, sS = 0.f, sC = 0.f;
#pragma unroll
      for (int ni = 0; ni < 4; ++ni) {
        float tv = accT[mi][ni][r], sv = accS[mi][ni][r];
        sT += tv * tv; sS += sv * sv; sC += tv * sv;
      }
#pragma unroll
      for (int msk = 1; msk < 16; msk <<= 1) {
        sT += __shfl_xor(sT, msk); sS += __shfl_xor(sS, msk); sC += __shfl_xor(sC, msk);
      }
      if (c0 == 0) {
        int m = tm * 128 + wr * 64 + mi * 16 + g * 4 + r;
        atomicAdd(pT + m, sT); atomicAdd(pS + m, sS); atomicAdd(pC + m, sC);
      }
    }
  // column-direction sums (transpose contribution), off-diagonal tiles only
  if (tm != tn) {
#pragma unroll
    for (int ni = 0; ni < 4; ++ni) {
      float sT = 0.f, sS = 0.f, sC = 0.f;
#pragma unroll
      for (int mi = 0; mi < 4; ++mi)
#pragma unroll
        for (int r = 0; r < 4; ++r) {
          float tv = accT[mi][ni][r], sv = accS[mi][ni][r];
          sT += tv * tv; sS += sv * sv; sC += tv * sv;
        }
      sT += __shfl_xor(sT, 16); sS += __shfl_xor(sS, 16); sC += __shfl_xor(sC, 16);
      sT += __shfl_xor(sT, 32); sS += __shfl_xor(sS, 32); sC += __shfl_xor(sC, 32);
      if (g == 0) {
        int n = tn * 128 + wc * 64 + ni * 16 + c0;
        atomicAdd(pT + n, sT); atomicAdd(pS + n, sS); atomicAdd(pC + n, sC);
      }
    }
  }
}

// ---------- kernel 4: channel grams, 2x2 register tiling, single pass over data ----------
__global__ void icgram2_kernel(const float* __restrict__ t_out, const float* __restrict__ s_out,
                               float* __restrict__ G) {
  __shared__ float lds[22 * 516];
  int chunk = blockIdx.x;   // 32 chunks of 512 m
  int z = blockIdx.y;       // t*16 + b
  int t = z >> 4, bb = z & 15;
  const float* L = (t ? s_out : t_out) + (size_t)bb * 21 * 16384 + (size_t)chunk * 512;
  int tid = threadIdx.x;    // 264 threads
  for (int idx = tid; idx < 22 * 128; idx += 264) {
    int r = idx >> 7, c = idx & 127;
    float4 v;
    if (r < 21) v = *reinterpret_cast<const float4*>(L + (size_t)r * 16384 + c * 4);
    else { v.x = 0.f; v.y = 0.f; v.z = 0.f; v.w = 0.f; }
    *reinterpret_cast<float4*>(&lds[r * 516 + c * 4]) = v;
  }
  __syncthreads();
  int ms = tid & 3, pb = tid >> 2;   // pb in [0,66)
  int p = pb, gi = 0;
  while (p >= 11 - gi) { p -= 11 - gi; gi++; }
  int gj = gi + p;
  const float* ri0 = &lds[(2 * gi) * 516 + ms * 128];
  const float* ri1 = ri0 + 516;
  const float* rj0 = &lds[(2 * gj) * 516 + ms * 128];
  const float* rj1 = rj0 + 516;
  float a00 = 0.f, a01 = 0.f, a10 = 0.f, a11 = 0.f;
#pragma unroll
  for (int mi = 0; mi < 32; ++mi) {
    float4 va0 = *reinterpret_cast<const float4*>(ri0 + mi * 4);
    float4 va1 = *reinterpret_cast<const float4*>(ri1 + mi * 4);
    float4 vb0 = *reinterpret_cast<const float4*>(rj0 + mi * 4);
    float4 vb1 = *reinterpret_cast<const float4*>(rj1 + mi * 4);
    a00 += va0.x * vb0.x + va0.y * vb0.y + va0.z * vb0.z + va0.w * vb0.w;
    a01 += va0.x * vb1.x + va0.y * vb1.y + va0.z * vb1.z + va0.w * vb1.w;
    a10 += va1.x * vb0.x + va1.y * vb0.y + va1.z * vb0.z + va1.w * vb0.w;
    a11 += va1.x * vb1.x + va1.y * vb1.y + va1.z * vb1.z + va1.w * vb1.w;
  }
  a00 += __shfl_xor(a00, 1); a00 += __shfl_xor(a00, 2);
  a01 += __shfl_xor(a01, 1); a01 += __shfl_xor(a01, 2);
  a10 += __shfl_xor(a10, 1); a10 += __shfl_xor(a10, 2);
  a11 += __shfl_xor(a11, 1); a11 += __shfl_xor(a11, 2);
  if (ms == 0) {
    float* Gz = G + (size_t)z * 441;
    int i0 = 2 * gi, i1 = i0 + 1, j0 = 2 * gj, j1 = j0 + 1;
    atomicAdd(&Gz[i0 * 21 + j0], a00);
    if (j1 < 21) atomicAdd(&Gz[i0 * 21 + j1], a01);
    if (i1 < 21 && gi != gj) atomicAdd(&Gz[i1 * 21 + j0], a10);
    if (i1 < 21 && j1 < 21) atomicAdd(&Gz[i1 * 21 + j1], a11);
  }
}

// ---------- kernel 5: finalize both losses ----------
__global__ void finalize_kernel(const float* __restrict__ G, const float* __restrict__ nT,
                                const float* __restrict__ nS, const float* __restrict__ cross,
                                float* __restrict__ out2) {
  __shared__ float red[8];
  int tid = threadIdx.x;   // 512
  float sa = 0.f;
  for (int idx = tid; idx < 16384; idx += 512) {
    float a = nT[idx], s = nS[idx], c = cross[idx];
    float NT = fmaxf(sqrtf(a), 1e-12f), NS = fmaxf(sqrtf(s), 1e-12f);
    sa += a / (NT * NT) + s / (NS * NS) - 2.f * c / (NT * NS);
  }
  float ic = 0.f;
  if (tid < 336) {
    int b = tid / 21, i = tid % 21;
    const float* gt = G + (size_t)b * 441;
    const float* gs = G + (size_t)(16 + b) * 441;
    float nt = 0.f, ns = 0.f;
    for (int j = 0; j < 21; ++j) {
      int idx2 = (i <= j) ? i * 21 + j : j * 21 + i;
      float vt = gt[idx2], vs = gs[idx2];
      nt += vt * vt; ns += vs * vs;
    }
    float rt = 1.f / fmaxf(sqrtf(nt), 1e-12f);
    float rs = 1.f / fmaxf(sqrtf(ns), 1e-12f);
    for (int j = 0; j < 21; ++j) {
      int idx2 = (i <= j) ? i * 21 + j : j * 21 + i;
      float d = gs[idx2] * rs - gt[idx2] * rt;
      ic += d * d;
    }
  }
  int lane = tid & 63, wv = tid >> 6;
#pragma unroll
  for (int m = 32; m; m >>= 1) { sa += __shfl_xor(sa, m); ic += __shfl_xor(ic, m); }
  if (lane == 0) red[wv] = sa;
  __syncthreads();
  if (tid == 0) { float s = 0.f; for (int w = 0; w < 8; ++w) s += red[w]; out2[1] = s * (1.0f / 16777216.0f); }
  __syncthreads();
  if (lane == 0) red[wv] = ic;
  __syncthreads();
  if (tid == 0) { float s = 0.f; for (int w = 0; w < 8; ++w) s += red[w]; out2[0] = s * (1.0f / 336.0f); }
}

// ---------- launch ----------
extern "C" void kernel_launch(void* const* d_in, const int* in_sizes, int n_in,
                              void* d_out, int out_size, void* d_ws, size_t ws_size,
                              hipStream_t stream) {
  const float* TF = (const float*)d_in[0];
  const float* SF = (const float*)d_in[1];
  const float* t_out = (const float*)d_in[2];
  const float* s_out = (const float*)d_in[3];
  float* out = (float*)d_out;
  char* ws = (char*)d_ws;

  // ws layout (bytes):
  //   0        : nT    [16][1024] f32  (65536)
  //   65536    : nS    [16][1024] f32  (65536)
  //   131072   : cross [16][1024] f32  (65536)
  //   196608   : G     [32][441]  f32  (56448, zeroed through 253056)
  //   253184   : sqrtFc [16384]   f32  (65536)
  //   318720   : Wt bf16 [16][1024][512] (16777216)
  //   17095936 : Ws bf16 [16][1024][512] (16777216)  -> total ~33.9 MB
  float* nT = (float*)(ws + 0);
  float* nS = (float*)(ws + 65536);
  float* cross = (float*)(ws + 131072);
  float* G = (float*)(ws + 196608);
  float* sqrtFc = (float*)(ws + 253184);
  __hip_bfloat16* Wt = (__hip_bfloat16*)(ws + 318720);
  __hip_bfloat16* Ws = (__hip_bfloat16*)(ws + 318720 + 16777216);

  hipMemcpyAsync(d_out, (const void*)s_out, (size_t)5505024 * 4, hipMemcpyDeviceToDevice, stream);
  hipMemsetAsync(ws, 0, 253056, stream);   // nT, nS, cross, G

  fc_kernel<<<4096, 256, 0, stream>>>(TF, SF, sqrtFc);
  wprep_kernel<<<dim3(32, 16, 32), 256, 0, stream>>>(TF, SF, sqrtFc, Wt, Ws);
  syrk_fused_kernel<<<dim3(36, 1, 16), 256, 0, stream>>>(Wt, Ws, nT, nS, cross);
  icgram2_kernel<<<dim3(32, 32), 264, 0, stream>>>(t_out, s_out, G);
  finalize_kernel<<<1, 512, 0, stream>>>(G, nT, nS, cross, out + 5505024);
}

// Round 3
// 125.803 us; speedup vs baseline: 1.7493x; 1.2137x over previous
//
#include <hip/hip_runtime.h>
#include <hip/hip_bf16.h>
#include <cstdint>
#include <cstddef>

// ---------- types ----------
typedef __bf16 bf16x8 __attribute__((ext_vector_type(8)));
typedef float f32x4 __attribute__((ext_vector_type(4)));

__device__ __forceinline__ void gload_lds16(const void* g, void* l) {
  __builtin_amdgcn_global_load_lds((const __attribute__((address_space(1))) void*)g,
                                   (__attribute__((address_space(3))) void*)l, 16, 0, 0);
}

// ---------- kernel 1: fused Fc + W prep ----------
// Block = (t, b, 16-channel group). Stage X[16][1024] f32 in LDS (stride 1028),
// compute per-channel sqrt(sum|x|), write W[m][c] = bf16(X[c][m]*scale[c]).
__global__ void __launch_bounds__(256) prep_kernel(const float* __restrict__ TF,
                                                   const float* __restrict__ SF,
                                                   __hip_bfloat16* __restrict__ Wt,
                                                   __hip_bfloat16* __restrict__ Ws) {
  __shared__ float Xs[16 * 1028];
  __shared__ float partial[4][16];
  __shared__ float scale[16];
  int id = blockIdx.x;              // [0,1024): t[1] b[4] cb[5]
  int t = id >> 9, b = (id >> 5) & 15, cb = id & 31;
  const float* Xg = (t ? SF : TF) + ((size_t)b * 512 + (size_t)cb * 16) * 1024;
  __hip_bfloat16* W = (t ? Ws : Wt) + (size_t)b * 524288 + cb * 16;
  int tid = threadIdx.x;
  // load 16 rows x 1024 f32, coalesced
#pragma unroll
  for (int it = 0; it < 16; ++it)
    *reinterpret_cast<float4*>(&Xs[it * 1028 + tid * 4]) =
        *reinterpret_cast<const float4*>(Xg + (size_t)it * 1024 + tid * 4);
  __syncthreads();
  // per-channel abs sums: row r = tid&15, segment seg = tid>>4 (16 segs of 64)
  {
    int r = tid & 15, seg = tid >> 4;
    float s = 0.f;
#pragma unroll
    for (int i = 0; i < 16; ++i) {
      float4 v = *reinterpret_cast<const float4*>(&Xs[r * 1028 + seg * 64 + i * 4]);
      s += fabsf(v.x) + fabsf(v.y) + fabsf(v.z) + fabsf(v.w);
    }
    s += __shfl_xor(s, 16); s += __shfl_xor(s, 32);
    if ((tid & 63) < 16) partial[tid >> 6][tid & 15] = s;
    __syncthreads();
    if (tid < 16) scale[tid] = sqrtf(partial[0][tid] + partial[1][tid] + partial[2][tid] + partial[3][tid]);
    __syncthreads();
  }
  float sc[16];
#pragma unroll
  for (int c = 0; c < 16; ++c) sc[c] = scale[c];
  // write W[m][cb*16..+16] for m = tid, +256, +512, +768 (32B stores)
#pragma unroll
  for (int j = 0; j < 4; ++j) {
    int m = j * 256 + tid;
    union { __hip_bfloat16 h[16]; uint4 u[2]; } pk;
#pragma unroll
    for (int c = 0; c < 16; ++c) pk.h[c] = __float2bfloat16(Xs[c * 1028 + m] * sc[c]);
    uint4* dst = reinterpret_cast<uint4*>(W + (size_t)m * 512);
    dst[0] = pk.u[0];
    dst[1] = pk.u[1];
  }
}

// ---------- SYRK staging: one 128x64 K-slice, chunk-XOR swizzled source ----------
__device__ __forceinline__ void stage_tile(const __hip_bfloat16* __restrict__ Wm,
                                           const __hip_bfloat16* __restrict__ Wn,
                                           __hip_bfloat16* As, __hip_bfloat16* Bs,
                                           int kt, bool diag) {
  int tid = threadIdx.x, wv = tid >> 6;
#pragma unroll
  for (int i = 0; i < 4; ++i) {
    int ci = i * 256 + tid;            // 16B chunk id, 1024 per tile
    int row = ci >> 3, slot = ci & 7;
    int gslot = slot ^ (row & 7);      // pre-swizzled global source (LDS dest linear)
    int wbase = (i * 256 + wv * 64) * 8;
    gload_lds16(Wm + (size_t)row * 512 + kt * 64 + gslot * 8, As + wbase);
    if (!diag)
      gload_lds16(Wn + (size_t)row * 512 + kt * 64 + gslot * 8, Bs + wbase);
  }
}

// ---------- kernel 2: fused SYRK, 2-phase pipelined, XCD-swizzled ----------
__global__ void __launch_bounds__(256, 2) syrk_fused_kernel(
    const __hip_bfloat16* __restrict__ Wt, const __hip_bfloat16* __restrict__ Ws,
    float* __restrict__ nT, float* __restrict__ nS, float* __restrict__ cross) {
  __shared__ __hip_bfloat16 As[2][128 * 64], Bs[2][128 * 64];   // 64 KB
  int lid = blockIdx.x;                       // 576 = 8 XCD * 72
  int swz = (lid & 7) * 72 + (lid >> 3);      // bijective XCD swizzle: 2 batches/XCD
  int b = swz / 36, tilec = swz % 36;
  int bx = tilec, tm = 0;
  while (bx >= 8 - tm) { bx -= 8 - tm; ++tm; }
  int tn = tm + bx;
  bool diag = (tm == tn);
  const __hip_bfloat16* WT = Wt + (size_t)b * 524288;
  const __hip_bfloat16* WS = Ws + (size_t)b * 524288;

  const int tid = threadIdx.x;
  const int lane = tid & 63, wv = tid >> 6;
  const int wr = wv >> 1, wc = wv & 1;
  const int g = lane >> 4, c0 = lane & 15;
  const int rx = c0 & 7;                      // row&7 for all this lane's frag rows

  f32x4 accT[4][4], accS[4][4];
#pragma unroll
  for (int mi = 0; mi < 4; ++mi)
#pragma unroll
    for (int ni = 0; ni < 4; ++ni) {
      accT[mi][ni] = (f32x4){0.f, 0.f, 0.f, 0.f};
      accS[mi][ni] = (f32x4){0.f, 0.f, 0.f, 0.f};
    }

  // prologue: stage step 0
  stage_tile(WT + (size_t)tm * 65536, WT + (size_t)tn * 65536, As[0], Bs[0], 0, diag);
  __syncthreads();

  for (int s = 0; s < 16; ++s) {              // steps: 0-7 = T, 8-15 = S
    int cur = s & 1;
    if (s < 15) {
      int s1 = s + 1;
      const __hip_bfloat16* base = (s1 < 8) ? WT : WS;
      stage_tile(base + (size_t)tm * 65536, base + (size_t)tn * 65536,
                 As[cur ^ 1], Bs[cur ^ 1], s1 & 7, diag);
    }
    const __hip_bfloat16* Asb = As[cur];
    const __hip_bfloat16* Bsb = diag ? As[cur] : Bs[cur];
    bool isT = (s < 8);
#pragma unroll
    for (int kk = 0; kk < 2; ++kk) {
      int chunk = ((kk * 4 + g) ^ rx) * 8;    // swizzled K-chunk element offset
      bf16x8 a[4], bb[4];
#pragma unroll
      for (int mi = 0; mi < 4; ++mi)
        a[mi] = *reinterpret_cast<const bf16x8*>(Asb + (wr * 64 + mi * 16 + c0) * 64 + chunk);
#pragma unroll
      for (int ni = 0; ni < 4; ++ni)
        bb[ni] = *reinterpret_cast<const bf16x8*>(Bsb + (wc * 64 + ni * 16 + c0) * 64 + chunk);
      if (isT) {
#pragma unroll
        for (int mi = 0; mi < 4; ++mi)
#pragma unroll
          for (int ni = 0; ni < 4; ++ni)
            accT[mi][ni] = __builtin_amdgcn_mfma_f32_16x16x32_bf16(a[mi], bb[ni], accT[mi][ni], 0, 0, 0);
      } else {
#pragma unroll
        for (int mi = 0; mi < 4; ++mi)
#pragma unroll
          for (int ni = 0; ni < 4; ++ni)
            accS[mi][ni] = __builtin_amdgcn_mfma_f32_16x16x32_bf16(a[mi], bb[ni], accS[mi][ni], 0, 0, 0);
      }
    }
    __syncthreads();                          // drains vmcnt+lgkmcnt: next buffer ready
  }

  float* pT = nT + (size_t)b * 1024;
  float* pS = nS + (size_t)b * 1024;
  float* pC = cross + (size_t)b * 1024;
  // row-direction sums (over columns of this tile)
#pragma unroll
  for (int mi = 0; mi < 4; ++mi)
#pragma unroll
    for (int r = 0; r < 4; ++r) {
      float sT = 0.f, sS = 0.f, sC = 0.f;
#pragma unroll
      for (int ni = 0; ni < 4; ++ni) {
        float tv = accT[mi][ni][r], sv = accS[mi][ni][r];
        sT += tv * tv; sS += sv * sv; sC += tv * sv;
      }
#pragma unroll
      for (int msk = 1; msk < 16; msk <<= 1) {
        sT += __shfl_xor(sT, msk); sS += __shfl_xor(sS, msk); sC += __shfl_xor(sC, msk);
      }
      if (c0 == 0) {
        int m = tm * 128 + wr * 64 + mi * 16 + g * 4 + r;
        atomicAdd(pT + m, sT); atomicAdd(pS + m, sS); atomicAdd(pC + m, sC);
      }
    }
  // column-direction sums (transpose contribution), off-diagonal only
  if (!diag) {
#pragma unroll
    for (int ni = 0; ni < 4; ++ni) {
      float sT = 0.f, sS = 0.f, sC = 0.f;
#pragma unroll
      for (int mi = 0; mi < 4; ++mi)
#pragma unroll
        for (int r = 0; r < 4; ++r) {
          float tv = accT[mi][ni][r], sv = accS[mi][ni][r];
          sT += tv * tv; sS += sv * sv; sC += tv * sv;
        }
      sT += __shfl_xor(sT, 16); sS += __shfl_xor(sS, 16); sC += __shfl_xor(sC, 16);
      sT += __shfl_xor(sT, 32); sS += __shfl_xor(sS, 32); sC += __shfl_xor(sC, 32);
      if (g == 0) {
        int n = tn * 128 + wc * 64 + ni * 16 + c0;
        atomicAdd(pT + n, sT); atomicAdd(pS + n, sS); atomicAdd(pC + n, sC);
      }
    }
  }
}

// ---------- kernel 3: channel grams, 2x2 register tiling, single pass ----------
__global__ void icgram2_kernel(const float* __restrict__ t_out, const float* __restrict__ s_out,
                               float* __restrict__ G) {
  __shared__ float lds[22 * 516];
  int chunk = blockIdx.x;   // 32 chunks of 512 m
  int z = blockIdx.y;       // t*16 + b
  int t = z >> 4, bb = z & 15;
  const float* L = (t ? s_out : t_out) + (size_t)bb * 21 * 16384 + (size_t)chunk * 512;
  int tid = threadIdx.x;    // 264 threads
  for (int idx = tid; idx < 22 * 128; idx += 264) {
    int r = idx >> 7, c = idx & 127;
    float4 v;
    if (r < 21) v = *reinterpret_cast<const float4*>(L + (size_t)r * 16384 + c * 4);
    else { v.x = 0.f; v.y = 0.f; v.z = 0.f; v.w = 0.f; }
    *reinterpret_cast<float4*>(&lds[r * 516 + c * 4]) = v;
  }
  __syncthreads();
  int ms = tid & 3, pb = tid >> 2;   // pb in [0,66)
  int p = pb, gi = 0;
  while (p >= 11 - gi) { p -= 11 - gi; gi++; }
  int gj = gi + p;
  const float* ri0 = &lds[(2 * gi) * 516 + ms * 128];
  const float* ri1 = ri0 + 516;
  const float* rj0 = &lds[(2 * gj) * 516 + ms * 128];
  const float* rj1 = rj0 + 516;
  float a00 = 0.f, a01 = 0.f, a10 = 0.f, a11 = 0.f;
#pragma unroll
  for (int mi = 0; mi < 32; ++mi) {
    float4 va0 = *reinterpret_cast<const float4*>(ri0 + mi * 4);
    float4 va1 = *reinterpret_cast<const float4*>(ri1 + mi * 4);
    float4 vb0 = *reinterpret_cast<const float4*>(rj0 + mi * 4);
    float4 vb1 = *reinterpret_cast<const float4*>(rj1 + mi * 4);
    a00 += va0.x * vb0.x + va0.y * vb0.y + va0.z * vb0.z + va0.w * vb0.w;
    a01 += va0.x * vb1.x + va0.y * vb1.y + va0.z * vb1.z + va0.w * vb1.w;
    a10 += va1.x * vb0.x + va1.y * vb0.y + va1.z * vb0.z + va1.w * vb0.w;
    a11 += va1.x * vb1.x + va1.y * vb1.y + va1.z * vb1.z + va1.w * vb1.w;
  }
  a00 += __shfl_xor(a00, 1); a00 += __shfl_xor(a00, 2);
  a01 += __shfl_xor(a01, 1); a01 += __shfl_xor(a01, 2);
  a10 += __shfl_xor(a10, 1); a10 += __shfl_xor(a10, 2);
  a11 += __shfl_xor(a11, 1); a11 += __shfl_xor(a11, 2);
  if (ms == 0) {
    float* Gz = G + (size_t)z * 441;
    int i0 = 2 * gi, i1 = i0 + 1, j0 = 2 * gj, j1 = j0 + 1;
    atomicAdd(&Gz[i0 * 21 + j0], a00);
    if (j1 < 21) atomicAdd(&Gz[i0 * 21 + j1], a01);
    if (i1 < 21 && gi != gj) atomicAdd(&Gz[i1 * 21 + j0], a10);
    if (i1 < 21 && j1 < 21) atomicAdd(&Gz[i1 * 21 + j1], a11);
  }
}

// ---------- kernel 4: finalize both losses ----------
__global__ void finalize_kernel(const float* __restrict__ G, const float* __restrict__ nT,
                                const float* __restrict__ nS, const float* __restrict__ cross,
                                float* __restrict__ out2) {
  __shared__ float red[16];
  int tid = threadIdx.x;   // 1024
  float sa = 0.f;
#pragma unroll
  for (int it = 0; it < 4; ++it) {
    int i4 = it * 1024 + tid;
    float4 a = reinterpret_cast<const float4*>(nT)[i4];
    float4 s4 = reinterpret_cast<const float4*>(nS)[i4];
    float4 c4 = reinterpret_cast<const float4*>(cross)[i4];
#pragma unroll
    for (int k = 0; k < 4; ++k) {
      float a1 = (&a.x)[k], s1 = (&s4.x)[k], c1 = (&c4.x)[k];
      float NT = fmaxf(sqrtf(a1), 1e-12f), NS = fmaxf(sqrtf(s1), 1e-12f);
      sa += a1 / (NT * NT) + s1 / (NS * NS) - 2.f * c1 / (NT * NS);
    }
  }
  float ic = 0.f;
  if (tid < 336) {
    int b = tid / 21, i = tid % 21;
    const float* gt = G + (size_t)b * 441;
    const float* gs = G + (size_t)(16 + b) * 441;
    float nt = 0.f, ns = 0.f;
    for (int j = 0; j < 21; ++j) {
      int idx2 = (i <= j) ? i * 21 + j : j * 21 + i;
      float vt = gt[idx2], vs = gs[idx2];
      nt += vt * vt; ns += vs * vs;
    }
    float rt = 1.f / fmaxf(sqrtf(nt), 1e-12f);
    float rs = 1.f / fmaxf(sqrtf(ns), 1e-12f);
    for (int j = 0; j < 21; ++j) {
      int idx2 = (i <= j) ? i * 21 + j : j * 21 + i;
      float d = gs[idx2] * rs - gt[idx2] * rt;
      ic += d * d;
    }
  }
  int lane = tid & 63, wv = tid >> 6;
#pragma unroll
  for (int m = 32; m; m >>= 1) { sa += __shfl_xor(sa, m); ic += __shfl_xor(ic, m); }
  if (lane == 0) red[wv] = sa;
  __syncthreads();
  if (tid == 0) { float s = 0.f; for (int w = 0; w < 16; ++w) s += red[w]; out2[1] = s * (1.0f / 16777216.0f); }
  __syncthreads();
  if (lane == 0) red[wv] = ic;
  __syncthreads();
  if (tid == 0) { float s = 0.f; for (int w = 0; w < 16; ++w) s += red[w]; out2[0] = s * (1.0f / 336.0f); }
}

// ---------- launch ----------
extern "C" void kernel_launch(void* const* d_in, const int* in_sizes, int n_in,
                              void* d_out, int out_size, void* d_ws, size_t ws_size,
                              hipStream_t stream) {
  const float* TF = (const float*)d_in[0];
  const float* SF = (const float*)d_in[1];
  const float* t_out = (const float*)d_in[2];
  const float* s_out = (const float*)d_in[3];
  float* out = (float*)d_out;
  char* ws = (char*)d_ws;

  // ws layout (bytes):
  //   0        : nT    [16][1024] f32  (65536)
  //   65536    : nS    [16][1024] f32  (65536)
  //   131072   : cross [16][1024] f32  (65536)
  //   196608   : G     [32][441]  f32  (56448, zeroed through 253056)
  //   262144   : Wt bf16 [16][1024][512] (16777216)
  //   17039360 : Ws bf16 [16][1024][512] (16777216)  -> total ~33.8 MB
  float* nT = (float*)(ws + 0);
  float* nS = (float*)(ws + 65536);
  float* cross = (float*)(ws + 131072);
  float* G = (float*)(ws + 196608);
  __hip_bfloat16* Wt = (__hip_bfloat16*)(ws + 262144);
  __hip_bfloat16* Ws = (__hip_bfloat16*)(ws + 262144 + 16777216);

  hipMemcpyAsync(d_out, (const void*)s_out, (size_t)5505024 * 4, hipMemcpyDeviceToDevice, stream);
  hipMemsetAsync(ws, 0, 253056, stream);   // nT, nS, cross, G

  prep_kernel<<<1024, 256, 0, stream>>>(TF, SF, Wt, Ws);
  syrk_fused_kernel<<<576, 256, 0, stream>>>(Wt, Ws, nT, nS, cross);
  icgram2_kernel<<<dim3(32, 32), 264, 0, stream>>>(t_out, s_out, G);
  finalize_kernel<<<1, 1024, 0, stream>>>(G, nT, nS, cross, out + 5505024);
}